// Round 3
// baseline (4469.202 us; speedup 1.0000x reference)
//
#include <hip/hip_runtime.h>
#include <hip/hip_bf16.h>

// Problem: B=128, L=400, D=1024, C=256
// Chain: h = emb@Wl+bl -> [B,C,L] -> net -> relu -> LN(g2) -> net -> net -> net -> [B,L,C]
// net: conv3(w0)+relu -> LN(g1) -> conv3(w1) -> conv3_dil2(w2)

#define BN 128
#define LL 400
#define DD 1024
#define CC 256

// ---------------------------------------------------------------------------
// GEMM: T0[m][n] = sum_k emb[m][k] * Wl[k][n] + bl[n]; M=51200, K=1024, N=256
// block 256 threads, tile 128x128, micro 8x8, K-chunk 16
// ---------------------------------------------------------------------------
__global__ __launch_bounds__(256) void gemm_k(
    const float* __restrict__ A,   // emb [M,K]
    const float* __restrict__ Bw,  // Wl  [K,N]
    const float* __restrict__ bl,  // [N]
    float* __restrict__ Cout)      // [M,N]
{
    __shared__ float As[16][132];   // [k][m] (padded stride)
    __shared__ float Bs[16][128];   // [k][n]

    const int tid = threadIdx.x;
    const int m0 = blockIdx.y * 128;
    const int n0 = blockIdx.x * 128;
    const int tx = tid & 15;        // n micro
    const int ty = tid >> 4;        // m micro

    float acc[8][8];
#pragma unroll
    for (int i = 0; i < 8; ++i)
#pragma unroll
        for (int j = 0; j < 8; ++j) acc[i][j] = 0.f;

    const int m_row = tid >> 1;           // 0..127
    const int k8 = (tid & 1) * 8;         // 0 or 8
    const int br = tid >> 4;              // 0..15
    const int bc8 = (tid & 15) * 8;       // 0..120  (FIX: full 128-col coverage)

    for (int kc = 0; kc < DD; kc += 16) {
        __syncthreads();
        // load A tile: As[k][m]
        {
            const float* src = A + (size_t)(m0 + m_row) * DD + kc + k8;
            float4 v0 = *reinterpret_cast<const float4*>(src);
            float4 v1 = *reinterpret_cast<const float4*>(src + 4);
            As[k8 + 0][m_row] = v0.x; As[k8 + 1][m_row] = v0.y;
            As[k8 + 2][m_row] = v0.z; As[k8 + 3][m_row] = v0.w;
            As[k8 + 4][m_row] = v1.x; As[k8 + 5][m_row] = v1.y;
            As[k8 + 6][m_row] = v1.z; As[k8 + 7][m_row] = v1.w;
        }
        // load B tile: Bs[k][n] — 16 rows x 128 cols, 8 floats/thread
        {
            const float* bsrc = Bw + (size_t)(kc + br) * CC + n0 + bc8;
            float4 v0 = *reinterpret_cast<const float4*>(bsrc);
            float4 v1 = *reinterpret_cast<const float4*>(bsrc + 4);
            *reinterpret_cast<float4*>(&Bs[br][bc8]) = v0;
            *reinterpret_cast<float4*>(&Bs[br][bc8 + 4]) = v1;
        }
        __syncthreads();
#pragma unroll
        for (int kk = 0; kk < 16; ++kk) {
            float a[8], b[8];
            *reinterpret_cast<float4*>(&a[0]) = *reinterpret_cast<const float4*>(&As[kk][ty * 8]);
            *reinterpret_cast<float4*>(&a[4]) = *reinterpret_cast<const float4*>(&As[kk][ty * 8 + 4]);
            *reinterpret_cast<float4*>(&b[0]) = *reinterpret_cast<const float4*>(&Bs[kk][tx * 8]);
            *reinterpret_cast<float4*>(&b[4]) = *reinterpret_cast<const float4*>(&Bs[kk][tx * 8 + 4]);
#pragma unroll
            for (int i = 0; i < 8; ++i)
#pragma unroll
                for (int j = 0; j < 8; ++j)
                    acc[i][j] = fmaf(a[i], b[j], acc[i][j]);
        }
    }

    float bv[8];
    *reinterpret_cast<float4*>(&bv[0]) = *reinterpret_cast<const float4*>(&bl[n0 + tx * 8]);
    *reinterpret_cast<float4*>(&bv[4]) = *reinterpret_cast<const float4*>(&bl[n0 + tx * 8 + 4]);
#pragma unroll
    for (int i = 0; i < 8; ++i) {
        float4 s0, s1;
        s0.x = acc[i][0] + bv[0]; s0.y = acc[i][1] + bv[1];
        s0.z = acc[i][2] + bv[2]; s0.w = acc[i][3] + bv[3];
        s1.x = acc[i][4] + bv[4]; s1.y = acc[i][5] + bv[5];
        s1.z = acc[i][6] + bv[6]; s1.w = acc[i][7] + bv[7];
        float* dst = Cout + (size_t)(m0 + ty * 8 + i) * CC + n0 + tx * 8;
        *reinterpret_cast<float4*>(dst) = s0;
        *reinterpret_cast<float4*>(dst + 4) = s1;
    }
}

// ---------------------------------------------------------------------------
// Transpose per-batch: in [B][R][C] -> out [B][C][R]
// ---------------------------------------------------------------------------
__global__ __launch_bounds__(256) void transpose_k(
    const float* __restrict__ in, float* __restrict__ out, int R, int C)
{
    __shared__ float s[32][33];
    const int b = blockIdx.z;
    const int c0 = blockIdx.x * 32, r0 = blockIdx.y * 32;
    const int tx = threadIdx.x, ty = threadIdx.y;
    const float* ib = in + (size_t)b * R * C;
    float* ob = out + (size_t)b * R * C;
#pragma unroll
    for (int j = 0; j < 32; j += 8) {
        int r = r0 + ty + j, c = c0 + tx;
        if (r < R && c < C) s[ty + j][tx] = ib[(size_t)r * C + c];
    }
    __syncthreads();
#pragma unroll
    for (int j = 0; j < 32; j += 8) {
        int c = c0 + ty + j, r = r0 + tx;
        if (r < R && c < C) ob[(size_t)c * R + r] = s[tx][ty + j];
    }
}

// ---------------------------------------------------------------------------
// Conv1d kernel-3 over L with dilation DIL, optional fused ReLU.
// x,y: [B,256,400]; w: [256,256,3]; grid (5, B); block 256 (4 waves)
// tile: 256 o x 80 l per block; wave owns 20 l; thread owns 4 o x 20 l
// ---------------------------------------------------------------------------
template<int DIL, bool RELU>
__global__ __launch_bounds__(256) void conv3k(
    const float* __restrict__ x, const float* __restrict__ w,
    const float* __restrict__ bias, float* __restrict__ y)
{
    const int b = blockIdx.y;
    const int lt = blockIdx.x * 80;
    const int tid = threadIdx.x;
    const int wave = tid >> 6;
    const int lane = tid & 63;
    const int l0 = lt + wave * 20;
    const int obase = lane * 4;

    __shared__ float xs[16][88];        // i-chunk x window [lt-4, lt+83]
    __shared__ float ws_[16][3][256];   // [i][k][o]

    float acc[4][20];
#pragma unroll
    for (int j = 0; j < 4; ++j) {
        const float bv = bias[obase + j];
#pragma unroll
        for (int l = 0; l < 20; ++l) acc[j][l] = bv;
    }

    const float* xb = x + (size_t)b * CC * LL;

    for (int ic = 0; ic < 16; ++ic) {
        const int i0 = ic * 16;
        __syncthreads();
        // x chunk: 16 rows x 88 cols, zero-padded at L boundaries
        for (int t = tid; t < 16 * 88; t += 256) {
            const int r = t / 88, cidx = t - r * 88;
            const int l = lt - 4 + cidx;
            xs[r][cidx] = (l >= 0 && l < LL) ? xb[(size_t)(i0 + r) * LL + l] : 0.f;
        }
        // w chunk: thread tid owns o=tid; 48 consecutive floats = 12 float4
        {
            const float4* wsrc = reinterpret_cast<const float4*>(w + (size_t)tid * 768 + i0 * 3);
#pragma unroll
            for (int r = 0; r < 12; ++r) {
                const float4 v = wsrc[r];
                const int f0 = r * 4;
                ws_[(f0 + 0) / 3][(f0 + 0) % 3][tid] = v.x;
                ws_[(f0 + 1) / 3][(f0 + 1) % 3][tid] = v.y;
                ws_[(f0 + 2) / 3][(f0 + 2) % 3][tid] = v.z;
                ws_[(f0 + 3) / 3][(f0 + 3) % 3][tid] = v.w;
            }
        }
        __syncthreads();

        for (int ii = 0; ii < 16; ++ii) {
            float xw[28];
            const float4* xsrc = reinterpret_cast<const float4*>(&xs[ii][wave * 20]);
#pragma unroll
            for (int q = 0; q < 7; ++q) {
                const float4 v = xsrc[q];
                xw[q * 4 + 0] = v.x; xw[q * 4 + 1] = v.y;
                xw[q * 4 + 2] = v.z; xw[q * 4 + 3] = v.w;
            }
            const float4 wv0 = *reinterpret_cast<const float4*>(&ws_[ii][0][obase]);
            const float4 wv1 = *reinterpret_cast<const float4*>(&ws_[ii][1][obase]);
            const float4 wv2 = *reinterpret_cast<const float4*>(&ws_[ii][2][obase]);
            const float wk0[4] = {wv0.x, wv0.y, wv0.z, wv0.w};
            const float wk1[4] = {wv1.x, wv1.y, wv1.z, wv1.w};
            const float wk2[4] = {wv2.x, wv2.y, wv2.z, wv2.w};
#pragma unroll
            for (int j = 0; j < 4; ++j)
#pragma unroll
                for (int l = 0; l < 20; ++l)
                    acc[j][l] = fmaf(wk0[j], xw[l + 4 - DIL],
                                fmaf(wk1[j], xw[l + 4],
                                fmaf(wk2[j], xw[l + 4 + DIL], acc[j][l])));
        }
    }

    float* yb = y + ((size_t)b * CC + obase) * LL + l0;
#pragma unroll
    for (int j = 0; j < 4; ++j) {
#pragma unroll
        for (int l = 0; l < 20; ++l) {
            float v = acc[j][l];
            if (RELU) v = fmaxf(v, 0.f);
            yb[(size_t)j * LL + l] = v;
        }
    }
}

// ---------------------------------------------------------------------------
// LayerNorm over last dim (L=400), per (b,c) row, torch semantics:
// unbiased std (ddof=1), y = g*(x-mean)/(std+eps) + be.  In-place.
// one wave per row; block 256 = 4 rows
// ---------------------------------------------------------------------------
__global__ __launch_bounds__(256) void lnk(
    float* __restrict__ xio, const float* __restrict__ g, const float* __restrict__ be)
{
    const int row = blockIdx.x * 4 + (threadIdx.x >> 6);
    const int lane = threadIdx.x & 63;
    float* xr = xio + (size_t)row * LL;

    float v[7];
    float s = 0.f, sq = 0.f;
#pragma unroll
    for (int q = 0; q < 7; ++q) {
        const int l = lane + q * 64;
        const float xv = (l < LL) ? xr[l] : 0.f;
        v[q] = xv; s += xv; sq = fmaf(xv, xv, sq);
    }
#pragma unroll
    for (int off = 32; off > 0; off >>= 1) {
        s += __shfl_xor(s, off);
        sq += __shfl_xor(sq, off);
    }
    const float mean = s * (1.f / LL);
    const float var = (sq - s * mean) * (1.f / (LL - 1));
    const float inv = 1.f / (sqrtf(fmaxf(var, 0.f)) + 1e-6f);
#pragma unroll
    for (int q = 0; q < 7; ++q) {
        const int l = lane + q * 64;
        if (l < LL) xr[l] = fmaf(g[l], (v[q] - mean) * inv, be[l]);
    }
}

// ---------------------------------------------------------------------------
static void launch_conv(int dil, bool relu, const float* in, float* out,
                        const float* w, const float* b, hipStream_t s)
{
    const dim3 g(5, BN);
    if (dil == 1) {
        if (relu) conv3k<1, true><<<g, 256, 0, s>>>(in, w, b, out);
        else      conv3k<1, false><<<g, 256, 0, s>>>(in, w, b, out);
    } else {
        if (relu) conv3k<2, true><<<g, 256, 0, s>>>(in, w, b, out);
        else      conv3k<2, false><<<g, 256, 0, s>>>(in, w, b, out);
    }
}

extern "C" void kernel_launch(void* const* d_in, const int* in_sizes, int n_in,
                              void* d_out, int out_size, void* d_ws, size_t ws_size,
                              hipStream_t stream)
{
    (void)in_sizes; (void)n_in; (void)out_size; (void)ws_size;

    const float* emb = (const float*)d_in[0];
    // d_in[1] = length (scalar, unused)
    const float* Wl  = (const float*)d_in[2];
    const float* bl  = (const float*)d_in[3];
    const float* w0  = (const float*)d_in[4];
    const float* b0  = (const float*)d_in[5];
    const float* w1  = (const float*)d_in[6];
    const float* b1  = (const float*)d_in[7];
    const float* w2  = (const float*)d_in[8];
    const float* b2  = (const float*)d_in[9];
    const float* g1  = (const float*)d_in[10];
    const float* be1 = (const float*)d_in[11];
    const float* g2  = (const float*)d_in[12];
    const float* be2 = (const float*)d_in[13];

    float* out = (float*)d_out;
    float* A = (float*)d_ws;     // 52.4 MB activation buffer
    float* Bb = out;             // reuse d_out as the second ping-pong buffer

    // 1) GEMM: emb@Wl+bl -> Bb as [B,L,C]
    gemm_k<<<dim3(CC / 128, (BN * LL) / 128), 256, 0, stream>>>(emb, Wl, bl, Bb);
    // 2) transpose [B,L,C] -> [B,C,L] into A
    transpose_k<<<dim3(CC / 32, (LL + 31) / 32, BN), dim3(32, 8), 0, stream>>>(Bb, A, LL, CC);

    auto run_ln = [&](float* buf, const float* g, const float* be) {
        lnk<<<(BN * CC) / 4, 256, 0, stream>>>(buf, g, be);
    };
    // net: conv0+relu -> LN(g1) -> conv1 -> conv3_dil2 ; maps X -> Y
    auto run_net = [&](float* X, float* Y, bool outer_relu) {
        launch_conv(1, true, X, Y, w0, b0, stream);
        run_ln(Y, g1, be1);
        launch_conv(1, false, Y, X, w1, b1, stream);
        launch_conv(2, outer_relu, X, Y, w2, b2, stream);
    };

    run_net(A, Bb, true);        // net1 + outer relu fused into last conv
    run_ln(Bb, g2, be2);         // outer LN(g2)
    run_net(Bb, A, false);       // net2  -> A
    run_net(A, Bb, false);       // net3  -> Bb
    run_net(Bb, A, false);       // net4  -> A
    // final transpose [B,C,L] -> [B,L,C] into d_out
    transpose_k<<<dim3((LL + 31) / 32, CC / 32, BN), dim3(32, 8), 0, stream>>>(A, out, CC, LL);
}

// Round 5
// 1684.196 us; speedup vs baseline: 2.6536x; 2.6536x over previous
//
#include <hip/hip_runtime.h>
#include <hip/hip_bf16.h>
#include <hip/hip_fp16.h>

// B=128, L=400, D=1024, C=256. All activations fp16 in [B][L][C] layout.
// Chain: GEMM(emb@Wl+bl) -> 4x net(conv3 w0 +relu, LN g1, conv3 w1, conv3 dil2 w2)
// with relu+LN(g2) after net1. Final conv writes f32 to d_out. No transposes needed.

#define BN 128
#define LL 400
#define DD 1024
#define CC 256

typedef _Float16 f16x8 __attribute__((ext_vector_type(8)));
typedef float f32x16 __attribute__((ext_vector_type(16)));
typedef unsigned short u16;
typedef unsigned int u32;

__device__ __forceinline__ u16 f2h(float f) {
    _Float16 h = (_Float16)f;
    return __builtin_bit_cast(u16, h);
}
__device__ __forceinline__ float h2f(u16 u) {
    return (float)__builtin_bit_cast(_Float16, u);
}

// ---------------------------------------------------------------------------
// Weight prep: w[o][i][k] f32 -> WB[k][o][i] f16   (3*256*256)
// ---------------------------------------------------------------------------
__global__ __launch_bounds__(256) void prep_w_k(
    const float* __restrict__ w, u16* __restrict__ wb)
{
    const int idx = blockIdx.x * 256 + threadIdx.x;
    if (idx >= 3 * CC * CC) return;
    const int k = idx >> 16;          // /(256*256)
    const int rem = idx & 65535;
    const int o = rem >> 8, i = rem & 255;
    wb[idx] = f2h(w[(o * CC + i) * 3 + k]);
}

// Wl[k][n] f32 -> WlT[n][k] f16   (256*1024)
__global__ __launch_bounds__(256) void prep_wl_k(
    const float* __restrict__ wl, u16* __restrict__ wlt)
{
    const int idx = blockIdx.x * 256 + threadIdx.x;
    const int n = idx >> 10, k = idx & 1023;
    wlt[idx] = f2h(wl[k * CC + n]);
}

// ---------------------------------------------------------------------------
// GEMM: out[m][n] = f16( emb[m][:] @ Wl[:][n] + bl[n] ), M=51200 K=1024 N=256
// mfma 32x32x16 f16. Block 256 thr (4 waves), tile 128m x 256n, K-step 16.
// LDS plane-split: [buf][k-half][row] of uint4 (16B = 8 f16), all frag reads
// and staging writes are contiguous-512B conflict-free b128 ops.
// ---------------------------------------------------------------------------
__global__ __launch_bounds__(256, 2) void gemm_mfma_k(
    const float* __restrict__ A, const u16* __restrict__ BT,
    const float* __restrict__ bias, u16* __restrict__ out)
{
    __shared__ uint4 As[2][2][128];
    __shared__ uint4 Bs[2][2][256];
    const int tid = threadIdx.x;
    const int lane = tid & 63, wid = tid >> 6;
    const int wl = wid >> 1, wo = wid & 1;
    const int ln = lane & 31, lp = lane >> 5;
    const int m0 = blockIdx.x * 128;

    const int ar = tid >> 1, ah = tid & 1;      // A granule (256 = 128 rows x 2)
    const int br = tid >> 1, bh = tid & 1;      // B granules: rows br, br+128

    f32x16 acc[2][4];
#pragma unroll
    for (int i = 0; i < 2; ++i)
#pragma unroll
        for (int j = 0; j < 4; ++j) acc[i][j] = (f32x16)(0.f);

    float av[8];
    uint4 bv0, bv1;

    auto gload = [&](int i0) {
        const float* asrc = A + (size_t)(m0 + ar) * DD + i0 + ah * 8;
        *reinterpret_cast<float4*>(&av[0]) = *reinterpret_cast<const float4*>(asrc);
        *reinterpret_cast<float4*>(&av[4]) = *reinterpret_cast<const float4*>(asrc + 4);
        bv0 = *reinterpret_cast<const uint4*>(BT + (size_t)br * DD + i0 + bh * 8);
        bv1 = *reinterpret_cast<const uint4*>(BT + (size_t)(br + 128) * DD + i0 + bh * 8);
    };
    auto swrite = [&](int buf) {
        f16x8 p;
#pragma unroll
        for (int j = 0; j < 8; ++j) p[j] = (_Float16)av[j];
        *reinterpret_cast<f16x8*>(&As[buf][ah][ar]) = p;
        Bs[buf][bh][br] = bv0;
        Bs[buf][bh][br + 128] = bv1;
    };

    gload(0);
    swrite(0);
    __syncthreads();

    for (int t = 0; t < 64; ++t) {
        const int buf = t & 1;
        if (t < 63) gload((t + 1) * 16);
        f16x8 af0 = *reinterpret_cast<const f16x8*>(&As[buf][lp][wl * 64 + ln]);
        f16x8 af1 = *reinterpret_cast<const f16x8*>(&As[buf][lp][wl * 64 + 32 + ln]);
#pragma unroll
        for (int fo = 0; fo < 4; ++fo) {
            f16x8 bf = *reinterpret_cast<const f16x8*>(&Bs[buf][lp][wo * 128 + fo * 32 + ln]);
            acc[0][fo] = __builtin_amdgcn_mfma_f32_32x32x16_f16(af0, bf, acc[0][fo], 0, 0, 0);
            acc[1][fo] = __builtin_amdgcn_mfma_f32_32x32x16_f16(af1, bf, acc[1][fo], 0, 0, 0);
        }
        if (t < 63) swrite(buf ^ 1);
        __syncthreads();
    }

#pragma unroll
    for (int fl = 0; fl < 2; ++fl) {
        const int mbase = m0 + wl * 64 + fl * 32;
#pragma unroll
        for (int fo = 0; fo < 4; ++fo) {
            const int n = wo * 128 + fo * 32 + ln;
            const float bv = bias[n];
#pragma unroll
            for (int r = 0; r < 16; ++r) {
                const int row = (r & 3) + 8 * (r >> 2) + 4 * lp;
                out[(size_t)(mbase + row) * CC + n] = f2h(acc[fl][fo][r] + bv);
            }
        }
    }
}

// ---------------------------------------------------------------------------
// Conv1d k=3 dilation DIL as 3 shifted GEMMs, mfma 32x32x16 f16.
// X,Y: [B][L][C] f16 (Y f32 if F32OUT). W: WB[k][o][i] f16. Block 256 thr,
// tile 128 l x 256 o; wave: 64l x 128o. K-step 16 i, 16 steps, double-buffered.
// ---------------------------------------------------------------------------
template<int DIL, bool RELU, bool F32OUT>
__global__ __launch_bounds__(256, 2) void conv_mfma_k(
    const u16* __restrict__ X, const u16* __restrict__ W,
    const float* __restrict__ bias, void* __restrict__ Yv)
{
    __shared__ uint4 XS[2][2][132];   // rows: l0-2 .. l0+129
    __shared__ uint4 WS[2][2][768];   // rows: k*256+o
    const int tid = threadIdx.x;
    const int lane = tid & 63, wid = tid >> 6;
    const int wl = wid >> 1, wo = wid & 1;
    const int ln = lane & 31, lp = lane >> 5;
    const int b = blockIdx.y, l0 = blockIdx.x * 128;

    const int xr = tid >> 1, xh = tid & 1;

    f32x16 acc[2][4];
#pragma unroll
    for (int i = 0; i < 2; ++i)
#pragma unroll
        for (int j = 0; j < 4; ++j) acc[i][j] = (f32x16)(0.f);

    uint4 xv0, xv1, wv[6];
    const uint4 z4 = make_uint4(0u, 0u, 0u, 0u);

    auto gload = [&](int i0) {
        {
            const int l = l0 - 2 + xr;
            xv0 = (l >= 0 && l < LL)
                ? *reinterpret_cast<const uint4*>(X + (size_t)(b * LL + l) * CC + i0 + xh * 8)
                : z4;
        }
        if (tid < 8) {
            const int l = l0 - 2 + 128 + (tid >> 1);
            xv1 = (l >= 0 && l < LL)
                ? *reinterpret_cast<const uint4*>(X + (size_t)(b * LL + l) * CC + i0 + (tid & 1) * 8)
                : z4;
        }
#pragma unroll
        for (int j = 0; j < 6; ++j) {
            const int g = tid + 256 * j;
            wv[j] = *reinterpret_cast<const uint4*>(W + (size_t)(g >> 1) * CC + i0 + (g & 1) * 8);
        }
    };
    auto swrite = [&](int buf) {
        XS[buf][xh][xr] = xv0;
        if (tid < 8) XS[buf][tid & 1][128 + (tid >> 1)] = xv1;
#pragma unroll
        for (int j = 0; j < 6; ++j) {
            const int g = tid + 256 * j;
            WS[buf][g & 1][g >> 1] = wv[j];
        }
    };

    gload(0);
    swrite(0);
    __syncthreads();

    for (int t = 0; t < 16; ++t) {
        const int buf = t & 1;
        if (t < 15) gload((t + 1) * 16);
#pragma unroll
        for (int s = 0; s < 3; ++s) {
            const int sh = 2 + (s - 1) * DIL;
            f16x8 a0 = *reinterpret_cast<const f16x8*>(&XS[buf][lp][wl * 64 + ln + sh]);
            f16x8 a1 = *reinterpret_cast<const f16x8*>(&XS[buf][lp][wl * 64 + 32 + ln + sh]);
#pragma unroll
            for (int fo = 0; fo < 4; ++fo) {
                f16x8 bf = *reinterpret_cast<const f16x8*>(&WS[buf][lp][s * 256 + wo * 128 + fo * 32 + ln]);
                acc[0][fo] = __builtin_amdgcn_mfma_f32_32x32x16_f16(a0, bf, acc[0][fo], 0, 0, 0);
                acc[1][fo] = __builtin_amdgcn_mfma_f32_32x32x16_f16(a1, bf, acc[1][fo], 0, 0, 0);
            }
        }
        if (t < 15) swrite(buf ^ 1);
        __syncthreads();
    }

#pragma unroll
    for (int fl = 0; fl < 2; ++fl) {
        const int lbase = l0 + wl * 64 + fl * 32;
#pragma unroll
        for (int fo = 0; fo < 4; ++fo) {
            const int o = wo * 128 + fo * 32 + ln;
            const float bv = bias[o];
#pragma unroll
            for (int r = 0; r < 16; ++r) {
                const int row = (r & 3) + 8 * (r >> 2) + 4 * lp;
                const int l = lbase + row;
                if (l < LL) {
                    float v = acc[fl][fo][r] + bv;
                    if (RELU) v = fmaxf(v, 0.f);
                    const size_t off = (size_t)(b * LL + l) * CC + o;
                    if (F32OUT) ((float*)Yv)[off] = v;
                    else        ((u16*)Yv)[off]  = f2h(v);
                }
            }
        }
    }
}

// ---------------------------------------------------------------------------
// LayerNorm over L per (b,c), torch semantics (ddof=1, /(std+eps)), in-place
// on f16 [B][L][C]. One wave per (b, c-half); thread owns 2 adjacent c.
// ---------------------------------------------------------------------------
__global__ __launch_bounds__(64) void ln_k(
    u16* __restrict__ X, const float* __restrict__ g, const float* __restrict__ be)
{
    const int bx = blockIdx.x;               // 256 = 128 b x 2 halves
    const int b = bx >> 1;
    const int c = (bx & 1) * 128 + threadIdx.x * 2;
    u16* base = X + (size_t)b * LL * CC + c;

    float s0 = 0.f, s1 = 0.f, q0 = 0.f, q1 = 0.f;
    for (int l = 0; l < LL; ++l) {
        const u32 v = *reinterpret_cast<const u32*>(base + (size_t)l * CC);
        const float f0 = h2f((u16)(v & 0xffff)), f1 = h2f((u16)(v >> 16));
        s0 += f0; q0 = fmaf(f0, f0, q0);
        s1 += f1; q1 = fmaf(f1, f1, q1);
    }
    const float m0 = s0 * (1.f / LL), m1 = s1 * (1.f / LL);
    const float v0 = (q0 - s0 * m0) * (1.f / (LL - 1));
    const float v1 = (q1 - s1 * m1) * (1.f / (LL - 1));
    const float i0 = 1.f / (sqrtf(fmaxf(v0, 0.f)) + 1e-6f);
    const float i1 = 1.f / (sqrtf(fmaxf(v1, 0.f)) + 1e-6f);

    for (int l = 0; l < LL; ++l) {
        const u32 v = *reinterpret_cast<const u32*>(base + (size_t)l * CC);
        const float f0 = h2f((u16)(v & 0xffff)), f1 = h2f((u16)(v >> 16));
        const float gl = g[l], bl = be[l];
        const float y0 = fmaf(gl, (f0 - m0) * i0, bl);
        const float y1 = fmaf(gl, (f1 - m1) * i1, bl);
        *reinterpret_cast<u32*>(base + (size_t)l * CC) =
            (u32)f2h(y0) | ((u32)f2h(y1) << 16);
    }
}

// ---------------------------------------------------------------------------
extern "C" void kernel_launch(void* const* d_in, const int* in_sizes, int n_in,
                              void* d_out, int out_size, void* d_ws, size_t ws_size,
                              hipStream_t stream)
{
    (void)in_sizes; (void)n_in; (void)out_size; (void)ws_size;

    const float* emb = (const float*)d_in[0];
    const float* Wl  = (const float*)d_in[2];
    const float* bl  = (const float*)d_in[3];
    const float* w0  = (const float*)d_in[4];
    const float* b0  = (const float*)d_in[5];
    const float* w1  = (const float*)d_in[6];
    const float* b1  = (const float*)d_in[7];
    const float* w2  = (const float*)d_in[8];
    const float* b2  = (const float*)d_in[9];
    const float* g1  = (const float*)d_in[10];
    const float* be1 = (const float*)d_in[11];
    const float* g2  = (const float*)d_in[12];
    const float* be2 = (const float*)d_in[13];

    // Buffers: Ta = d_out reused as f16 ping (26.2MB of 52.4MB), Tb = d_ws.
    // Weights packed after Tb in d_ws. Final conv reads Tb, writes f32 d_out.
    u16* Ta = (u16*)d_out;
    u16* Tb = (u16*)d_ws;
    char* wsb = (char*)d_ws + (size_t)BN * LL * CC * 2;   // +26,214,400
    u16* WB0 = (u16*)(wsb);
    u16* WB1 = (u16*)(wsb + 393216);
    u16* WB2 = (u16*)(wsb + 2 * 393216);
    u16* WlT = (u16*)(wsb + 3 * 393216);

    prep_w_k<<<768, 256, 0, stream>>>(w0, WB0);
    prep_w_k<<<768, 256, 0, stream>>>(w1, WB1);
    prep_w_k<<<768, 256, 0, stream>>>(w2, WB2);
    prep_wl_k<<<1024, 256, 0, stream>>>(Wl, WlT);

    // GEMM -> Ta
    gemm_mfma_k<<<(BN * LL) / 128, 256, 0, stream>>>(emb, WlT, bl, Ta);

    const dim3 cg(4, BN);
    auto ln = [&](u16* buf, const float* g, const float* be) {
        ln_k<<<2 * BN, 64, 0, stream>>>(buf, g, be);
    };

    // net1: c1 Ta->Tb (+relu) ; LN g1 ; c2 Tb->Ta ; c3 Ta->Tb (+outer relu) ; LN g2
    conv_mfma_k<1, true,  false><<<cg, 256, 0, stream>>>(Ta, WB0, b0, Tb);
    ln(Tb, g1, be1);
    conv_mfma_k<1, false, false><<<cg, 256, 0, stream>>>(Tb, WB1, b1, Ta);
    conv_mfma_k<2, true,  false><<<cg, 256, 0, stream>>>(Ta, WB2, b2, Tb);
    ln(Tb, g2, be2);
    // net2: Tb->Ta ; LN ; Ta->Tb ; Tb->Ta
    conv_mfma_k<1, true,  false><<<cg, 256, 0, stream>>>(Tb, WB0, b0, Ta);
    ln(Ta, g1, be1);
    conv_mfma_k<1, false, false><<<cg, 256, 0, stream>>>(Ta, WB1, b1, Tb);
    conv_mfma_k<2, false, false><<<cg, 256, 0, stream>>>(Tb, WB2, b2, Ta);
    // net3: Ta->Tb ; LN ; Tb->Ta ; Ta->Tb
    conv_mfma_k<1, true,  false><<<cg, 256, 0, stream>>>(Ta, WB0, b0, Tb);
    ln(Tb, g1, be1);
    conv_mfma_k<1, false, false><<<cg, 256, 0, stream>>>(Tb, WB1, b1, Ta);
    conv_mfma_k<2, false, false><<<cg, 256, 0, stream>>>(Ta, WB2, b2, Tb);
    // net4: Tb->Ta ; LN ; Ta->Tb ; Tb->d_out (f32)
    conv_mfma_k<1, true,  false><<<cg, 256, 0, stream>>>(Tb, WB0, b0, Ta);
    ln(Ta, g1, be1);
    conv_mfma_k<1, false, false><<<cg, 256, 0, stream>>>(Ta, WB1, b1, Tb);
    conv_mfma_k<2, false, true ><<<cg, 256, 0, stream>>>(Tb, WB2, b2, (float*)d_out);
}

// Round 6
// 1334.766 us; speedup vs baseline: 3.3483x; 1.2618x over previous
//
#include <hip/hip_runtime.h>
#include <hip/hip_bf16.h>
#include <hip/hip_fp16.h>

// B=128, L=400, D=1024, C=256.
// Activations: f16 granule layout [b][ic=0..15][ih=0..1][r=0..403][e=0..7],
// granule(16B) index aidx = ((b*16+ic)*2+ih)*404 + r, element c = ic*16+ih*8+e,
// row r = l+2 (rows 0,1,402,403 are zero pads). This is EXACTLY the per-K-step
// LDS staging order, so all staging loads are lane-contiguous.
// Weights pre-packed to LDS-image order likewise.

#define BN 128
#define LL 400
#define DD 1024
#define CC 256
#define RP 404
#define ACT_GRANULES (BN * 32 * RP)          // 1,654,784 granules (26.5 MB)

typedef _Float16 f16x8 __attribute__((ext_vector_type(8)));
typedef float f32x16 __attribute__((ext_vector_type(16)));
typedef unsigned short u16;
typedef unsigned int u32;

__device__ __forceinline__ u16 f2h(float f) { _Float16 h = (_Float16)f; return __builtin_bit_cast(u16, h); }
__device__ __forceinline__ float h2f(u16 u) { return (float)__builtin_bit_cast(_Float16, u); }
__device__ __forceinline__ u32 pk2(float a, float b) { return (u32)f2h(a) | ((u32)f2h(b) << 16); }

// ---------------------------------------------------------------------------
// Zero the pad rows (r in {0,1,402,403}) of both activation buffers.
// 2 bufs x 4096 planes x 4 granules = 32768 granules.
// ---------------------------------------------------------------------------
__global__ __launch_bounds__(256) void pad_zero_k(uint4* __restrict__ Ta, uint4* __restrict__ Tb)
{
    const int idx = blockIdx.x * 256 + threadIdx.x;      // 0..32767
    const int buf = idx >> 14;
    const int rem = idx & 16383;
    const int r4 = rem & 3;
    const int r = (r4 < 2) ? r4 : 400 + r4;
    const int plane = rem >> 2;                           // 0..4095
    (buf ? Tb : Ta)[(size_t)plane * RP + r] = make_uint4(0u, 0u, 0u, 0u);
}

// ---------------------------------------------------------------------------
// Pack conv weights w[o][i][k] f32 -> LDS-image granules:
// gi = t*1536 + ih*768 + k*256 + o, elems e: w[o][t*16+ih*8+e][k]. 24576 granules.
// ---------------------------------------------------------------------------
__global__ __launch_bounds__(256) void prep_w_pack_k(
    const float* __restrict__ w, uint4* __restrict__ dst)
{
    const int gi = blockIdx.x * 256 + threadIdx.x;
    if (gi >= 24576) return;
    const int t = gi / 1536;
    const int rem = gi - t * 1536;
    const int ih = rem / 768;
    const int rem2 = rem - ih * 768;
    const int k = rem2 >> 8, o = rem2 & 255;
    const int ibase = t * 16 + ih * 8;
    float v[8];
#pragma unroll
    for (int e = 0; e < 8; ++e) v[e] = w[(size_t)(o * CC + ibase + e) * 3 + k];
    uint4 p;
    p.x = pk2(v[0], v[1]); p.y = pk2(v[2], v[3]);
    p.z = pk2(v[4], v[5]); p.w = pk2(v[6], v[7]);
    dst[gi] = p;
}

// Pack Wl[k][n] f32 -> gi = t*512 + bh*256 + n, elems e: Wl[t*16+bh*8+e][n]. 32768 granules.
__global__ __launch_bounds__(256) void prep_wl_pack_k(
    const float* __restrict__ wl, uint4* __restrict__ dst)
{
    const int gi = blockIdx.x * 256 + threadIdx.x;       // < 32768
    const int t = gi >> 9;
    const int rem = gi & 511;
    const int bh = rem >> 8, n = rem & 255;
    const int kbase = t * 16 + bh * 8;
    float v[8];
#pragma unroll
    for (int e = 0; e < 8; ++e) v[e] = wl[(size_t)(kbase + e) * CC + n];
    uint4 p;
    p.x = pk2(v[0], v[1]); p.y = pk2(v[2], v[3]);
    p.z = pk2(v[4], v[5]); p.w = pk2(v[6], v[7]);
    dst[gi] = p;
}

// ---------------------------------------------------------------------------
// GEMM: emb[m][:] @ Wl + bl -> packed f16 activations. M=51200 K=1024 N=256.
// mfma 32x32x16 f16, tile 128m x 256n, K-step 16, double-buffered.
// ---------------------------------------------------------------------------
__global__ __launch_bounds__(256, 2) void gemm_mfma_k(
    const float* __restrict__ A, const uint4* __restrict__ BP,
    const float* __restrict__ bias, u16* __restrict__ out)
{
    __shared__ uint4 As[2][2][128];
    __shared__ uint4 Bs[2][2][256];
    const int tid = threadIdx.x;
    const int lane = tid & 63, wid = tid >> 6;
    const int wl = wid >> 1, wo = wid & 1;
    const int ln = lane & 31, lp = lane >> 5;
    const int m0 = blockIdx.x * 128;

    const int ar = tid >> 1, ah = tid & 1;

    f32x16 acc[2][4];
#pragma unroll
    for (int i = 0; i < 2; ++i)
#pragma unroll
        for (int j = 0; j < 4; ++j) acc[i][j] = (f32x16)(0.f);

    float av[8];
    uint4 bv0, bv1;

    auto gload = [&](int i0) {
        const float* asrc = A + (size_t)(m0 + ar) * DD + i0 + ah * 8;
        *reinterpret_cast<float4*>(&av[0]) = *reinterpret_cast<const float4*>(asrc);
        *reinterpret_cast<float4*>(&av[4]) = *reinterpret_cast<const float4*>(asrc + 4);
        const int t = i0 >> 4;
        bv0 = BP[t * 512 + tid];
        bv1 = BP[t * 512 + 256 + tid];
    };
    auto swrite = [&](int buf) {
        uint4 p;
        p.x = pk2(av[0], av[1]); p.y = pk2(av[2], av[3]);
        p.z = pk2(av[4], av[5]); p.w = pk2(av[6], av[7]);
        As[buf][ah][ar] = p;
        Bs[buf][0][tid] = bv0;
        Bs[buf][1][tid] = bv1;
    };

    gload(0);
    swrite(0);
    __syncthreads();

    for (int t = 0; t < 64; ++t) {
        const int buf = t & 1;
        if (t < 63) gload((t + 1) * 16);
        f16x8 af0 = *reinterpret_cast<const f16x8*>(&As[buf][lp][wl * 64 + ln]);
        f16x8 af1 = *reinterpret_cast<const f16x8*>(&As[buf][lp][wl * 64 + 32 + ln]);
#pragma unroll
        for (int fo = 0; fo < 4; ++fo) {
            f16x8 bf = *reinterpret_cast<const f16x8*>(&Bs[buf][lp][wo * 128 + fo * 32 + ln]);
            acc[0][fo] = __builtin_amdgcn_mfma_f32_32x32x16_f16(af0, bf, acc[0][fo], 0, 0, 0);
            acc[1][fo] = __builtin_amdgcn_mfma_f32_32x32x16_f16(af1, bf, acc[1][fo], 0, 0, 0);
        }
        if (t < 63) swrite(buf ^ 1);
        __syncthreads();
    }

#pragma unroll
    for (int fl = 0; fl < 2; ++fl) {
        const int mbase = m0 + wl * 64 + fl * 32;
#pragma unroll
        for (int fo = 0; fo < 4; ++fo) {
            const int n = wo * 128 + fo * 32 + ln;
            const float bv = bias[n];
            const int nc = n >> 4, nh = (n >> 3) & 1, ne = n & 7;
#pragma unroll
            for (int r = 0; r < 16; ++r) {
                const int mrow = mbase + (r & 3) + 8 * (r >> 2) + 4 * lp;
                const int b = mrow / LL;
                const int l = mrow - b * LL;
                const size_t gr = ((size_t)(b * 16 + nc) * 2 + nh) * RP + l + 2;
                out[gr * 8 + ne] = f2h(acc[fl][fo][r] + bv);
            }
        }
    }
}

// ---------------------------------------------------------------------------
// Conv1d k=3 dil DIL as 3 shifted GEMMs, mfma 32x32x16 f16, packed act layout.
// Block: tile 128 l x 256 o; 16 K-steps of 16 i; double-buffered.
// ---------------------------------------------------------------------------
template<int DIL, bool RELU, bool F32OUT>
__global__ __launch_bounds__(256, 2) void conv_mfma_k(
    const uint4* __restrict__ X4, const uint4* __restrict__ W4,
    const float* __restrict__ bias, void* __restrict__ Yv)
{
    __shared__ uint4 XS[2][2][132];
    __shared__ uint4 WS[2][2][768];
    const int tid = threadIdx.x;
    const int lane = tid & 63, wid = tid >> 6;
    const int wl = wid >> 1, wo = wid & 1;
    const int ln = lane & 31, lp = lane >> 5;
    const int b = blockIdx.y, l0 = blockIdx.x * 128;

    // X granules: gi0 = tid (plane = tid>=132), gi1 = 256+tid for tid<8 (plane 1)
    const int g0p = (tid >= 132) ? 1 : 0;
    const int g0r = tid - 132 * g0p;
    const int g1r = 124 + tid;                 // plane 1, only tid<8

    f32x16 acc[2][4];
#pragma unroll
    for (int i = 0; i < 2; ++i)
#pragma unroll
        for (int j = 0; j < 4; ++j) acc[i][j] = (f32x16)(0.f);

    uint4 xv0, xv1, wv[6];
    const uint4 z4 = make_uint4(0u, 0u, 0u, 0u);

    auto gload = [&](int t) {
        {
            const int r = l0 + g0r;
            xv0 = (r <= 403) ? X4[((size_t)(b * 16 + t) * 2 + g0p) * RP + r] : z4;
        }
        if (tid < 8) {
            const int r = l0 + g1r;
            xv1 = (r <= 403) ? X4[((size_t)(b * 16 + t) * 2 + 1) * RP + r] : z4;
        }
        const uint4* wsrc = W4 + t * 1536;
#pragma unroll
        for (int j = 0; j < 6; ++j) wv[j] = wsrc[j * 256 + tid];
    };
    auto swrite = [&](int buf) {
        XS[buf][g0p][g0r] = xv0;
        if (tid < 8) XS[buf][1][g1r] = xv1;
#pragma unroll
        for (int j = 0; j < 6; ++j) {
            const int pl = (j >= 3) ? 1 : 0;
            WS[buf][pl][(j - 3 * pl) * 256 + tid] = wv[j];
        }
    };

    gload(0);
    swrite(0);
    __syncthreads();

    for (int t = 0; t < 16; ++t) {
        const int buf = t & 1;
        if (t < 15) gload(t + 1);
#pragma unroll
        for (int s = 0; s < 3; ++s) {
            const int sh = 2 + (s - 1) * DIL;
            f16x8 a0 = *reinterpret_cast<const f16x8*>(&XS[buf][lp][wl * 64 + ln + sh]);
            f16x8 a1 = *reinterpret_cast<const f16x8*>(&XS[buf][lp][wl * 64 + 32 + ln + sh]);
#pragma unroll
            for (int fo = 0; fo < 4; ++fo) {
                f16x8 bf = *reinterpret_cast<const f16x8*>(&WS[buf][lp][s * 256 + wo * 128 + fo * 32 + ln]);
                acc[0][fo] = __builtin_amdgcn_mfma_f32_32x32x16_f16(a0, bf, acc[0][fo], 0, 0, 0);
                acc[1][fo] = __builtin_amdgcn_mfma_f32_32x32x16_f16(a1, bf, acc[1][fo], 0, 0, 0);
            }
        }
        if (t < 15) swrite(buf ^ 1);
        __syncthreads();
    }

#pragma unroll
    for (int fl = 0; fl < 2; ++fl) {
        const int lbase = l0 + wl * 64 + fl * 32;
#pragma unroll
        for (int fo = 0; fo < 4; ++fo) {
            const int o = wo * 128 + fo * 32 + ln;
            const float bv = bias[o];
            const int oc = o >> 4, oh = (o >> 3) & 1, oe = o & 7;
#pragma unroll
            for (int r = 0; r < 16; ++r) {
                const int l = lbase + (r & 3) + 8 * (r >> 2) + 4 * lp;
                if (l < LL) {
                    float v = acc[fl][fo][r] + bv;
                    if (RELU) v = fmaxf(v, 0.f);
                    if (F32OUT) {
                        ((float*)Yv)[((size_t)b * LL + l) * CC + o] = v;
                    } else {
                        const size_t gr = ((size_t)(b * 16 + oc) * 2 + oh) * RP + l + 2;
                        ((u16*)Yv)[gr * 8 + oe] = f2h(v);
                    }
                }
            }
        }
    }
}

// ---------------------------------------------------------------------------
// LayerNorm over l (torch ddof=1, /(std+eps)) on packed layout, in place.
// Block = one wave per (b, ic): lane = plane(ih) + row-half; 13 coalesced
// granule loads held in registers, stats via shfl_xor, pass-2 from regs.
// ---------------------------------------------------------------------------
__global__ __launch_bounds__(64) void ln_k(
    uint4* __restrict__ A4, const float* __restrict__ g, const float* __restrict__ be)
{
    const int bx = blockIdx.x;                 // b*16 + ic
    const int ln = threadIdx.x;
    const int ih = ln & 1, half = ln >> 1;
    uint4* base = A4 + ((size_t)bx * 2 + ih) * RP;

    float s[8], q[8];
#pragma unroll
    for (int e = 0; e < 8; ++e) { s[e] = 0.f; q[e] = 0.f; }
    uint4 xg[13];
    float gv[13], bv[13];

#pragma unroll
    for (int it = 0; it < 13; ++it) {
        const int r = 2 + it * 32 + half;
        const bool act = (r < 402);
        uint4 v = act ? base[r] : make_uint4(0u, 0u, 0u, 0u);
        gv[it] = act ? g[r - 2] : 0.f;
        bv[it] = act ? be[r - 2] : 0.f;
        xg[it] = v;
        const u32 w[4] = {v.x, v.y, v.z, v.w};
#pragma unroll
        for (int p = 0; p < 4; ++p) {
            const float f0 = h2f((u16)(w[p] & 0xffff));
            const float f1 = h2f((u16)(w[p] >> 16));
            s[2 * p] += f0;     q[2 * p] = fmaf(f0, f0, q[2 * p]);
            s[2 * p + 1] += f1; q[2 * p + 1] = fmaf(f1, f1, q[2 * p + 1]);
        }
    }
#pragma unroll
    for (int off = 2; off < 64; off <<= 1) {
#pragma unroll
        for (int e = 0; e < 8; ++e) {
            s[e] += __shfl_xor(s[e], off);
            q[e] += __shfl_xor(q[e], off);
        }
    }
    float mean[8], inv[8];
#pragma unroll
    for (int e = 0; e < 8; ++e) {
        mean[e] = s[e] * (1.f / LL);
        const float var = (q[e] - s[e] * mean[e]) * (1.f / (LL - 1));
        inv[e] = 1.f / (sqrtf(fmaxf(var, 0.f)) + 1e-6f);
    }
#pragma unroll
    for (int it = 0; it < 13; ++it) {
        const int r = 2 + it * 32 + half;
        if (r < 402) {
            const uint4 v = xg[it];
            const u32 w[4] = {v.x, v.y, v.z, v.w};
            const float gl = gv[it], bl = bv[it];
            uint4 o;
            u32 ow[4];
#pragma unroll
            for (int p = 0; p < 4; ++p) {
                const float f0 = h2f((u16)(w[p] & 0xffff));
                const float f1 = h2f((u16)(w[p] >> 16));
                const float y0 = fmaf(gl, (f0 - mean[2 * p]) * inv[2 * p], bl);
                const float y1 = fmaf(gl, (f1 - mean[2 * p + 1]) * inv[2 * p + 1], bl);
                ow[p] = pk2(y0, y1);
            }
            o.x = ow[0]; o.y = ow[1]; o.z = ow[2]; o.w = ow[3];
            base[r] = o;
        }
    }
}

// ---------------------------------------------------------------------------
extern "C" void kernel_launch(void* const* d_in, const int* in_sizes, int n_in,
                              void* d_out, int out_size, void* d_ws, size_t ws_size,
                              hipStream_t stream)
{
    (void)in_sizes; (void)n_in; (void)out_size; (void)ws_size;

    const float* emb = (const float*)d_in[0];
    const float* Wl  = (const float*)d_in[2];
    const float* bl  = (const float*)d_in[3];
    const float* w0  = (const float*)d_in[4];
    const float* b0  = (const float*)d_in[5];
    const float* w1  = (const float*)d_in[6];
    const float* b1  = (const float*)d_in[7];
    const float* w2  = (const float*)d_in[8];
    const float* b2  = (const float*)d_in[9];
    const float* g1  = (const float*)d_in[10];
    const float* be1 = (const float*)d_in[11];
    const float* g2  = (const float*)d_in[12];
    const float* be2 = (const float*)d_in[13];

    uint4* Ta = (uint4*)d_out;                  // packed f16 act ping (26.5 MB of 52.4)
    uint4* Tb = (uint4*)d_ws;                   // packed f16 act pong
    uint4* WB0 = Tb + ACT_GRANULES;
    uint4* WB1 = WB0 + 24576;
    uint4* WB2 = WB1 + 24576;
    uint4* WlP = WB2 + 24576;

    pad_zero_k<<<128, 256, 0, stream>>>(Ta, Tb);
    prep_w_pack_k<<<96, 256, 0, stream>>>(w0, WB0);
    prep_w_pack_k<<<96, 256, 0, stream>>>(w1, WB1);
    prep_w_pack_k<<<96, 256, 0, stream>>>(w2, WB2);
    prep_wl_pack_k<<<128, 256, 0, stream>>>(Wl, WlP);

    gemm_mfma_k<<<(BN * LL) / 128, 256, 0, stream>>>(emb, WlP, bl, (u16*)Ta);

    const dim3 cg(4, BN);
    auto ln = [&](uint4* buf, const float* g, const float* be) {
        ln_k<<<16 * BN, 64, 0, stream>>>(buf, g, be);
    };

    // net1 (+outer relu fused into c3) + LN(g2)
    conv_mfma_k<1, true,  false><<<cg, 256, 0, stream>>>(Ta, WB0, b0, Tb);
    ln(Tb, g1, be1);
    conv_mfma_k<1, false, false><<<cg, 256, 0, stream>>>(Tb, WB1, b1, Ta);
    conv_mfma_k<2, true,  false><<<cg, 256, 0, stream>>>(Ta, WB2, b2, Tb);
    ln(Tb, g2, be2);
    // net2
    conv_mfma_k<1, true,  false><<<cg, 256, 0, stream>>>(Tb, WB0, b0, Ta);
    ln(Ta, g1, be1);
    conv_mfma_k<1, false, false><<<cg, 256, 0, stream>>>(Ta, WB1, b1, Tb);
    conv_mfma_k<2, false, false><<<cg, 256, 0, stream>>>(Tb, WB2, b2, Ta);
    // net3
    conv_mfma_k<1, true,  false><<<cg, 256, 0, stream>>>(Ta, WB0, b0, Tb);
    ln(Tb, g1, be1);
    conv_mfma_k<1, false, false><<<cg, 256, 0, stream>>>(Tb, WB1, b1, Ta);
    conv_mfma_k<2, false, false><<<cg, 256, 0, stream>>>(Ta, WB2, b2, Tb);
    // net4 -> final conv reads Tb(=d_ws), writes f32 [B][L][C] to d_out
    conv_mfma_k<1, true,  false><<<cg, 256, 0, stream>>>(Tb, WB0, b0, Ta);
    ln(Ta, g1, be1);
    conv_mfma_k<1, false, false><<<cg, 256, 0, stream>>>(Ta, WB1, b1, Tb);
    conv_mfma_k<2, false, true ><<<cg, 256, 0, stream>>>(Tb, WB2, b2, (float*)d_out);
}

// Round 7
// 932.949 us; speedup vs baseline: 4.7904x; 1.4307x over previous
//
#include <hip/hip_runtime.h>
#include <hip/hip_bf16.h>
#include <hip/hip_fp16.h>

// B=128, L=400, D=1024, C=256.
// Activations: f16 granule layout [b][ic=0..15][ih=0..1][r=0..403][e=0..7],
// granule(16B) index = ((b*16+ic)*2+ih)*404 + r, element c = ic*16+ih*8+e,
// row r = l+2 (rows 0,1,402,403 zero pads -> OOB handling by address clamp).
// Staging uses global_load_lds width=16: linear LDS dest, per-lane global src.

#define BN 128
#define LL 400
#define DD 1024
#define CC 256
#define RP 404
#define ACT_GRANULES (BN * 32 * RP)

typedef _Float16 f16x8 __attribute__((ext_vector_type(8)));
typedef float f32x16 __attribute__((ext_vector_type(16)));
typedef unsigned short u16;
typedef unsigned int u32;

typedef __attribute__((address_space(3))) uint4 lds_uint4;
typedef __attribute__((address_space(1))) const uint4 glob_uint4;

__device__ __forceinline__ void gld16(const uint4* g, uint4* l) {
    __builtin_amdgcn_global_load_lds((glob_uint4*)g, (lds_uint4*)l, 16, 0, 0);
}

__device__ __forceinline__ u16 f2h(float f) { _Float16 h = (_Float16)f; return __builtin_bit_cast(u16, h); }
__device__ __forceinline__ float h2f(u16 u) { return (float)__builtin_bit_cast(_Float16, u); }
__device__ __forceinline__ u32 pk2(float a, float b) { return (u32)f2h(a) | ((u32)f2h(b) << 16); }

// ---------------------------------------------------------------------------
// Zero pad rows (r in {0,1,402,403}) of both activation buffers.
// ---------------------------------------------------------------------------
__global__ __launch_bounds__(256) void pad_zero_k(uint4* __restrict__ Ta, uint4* __restrict__ Tb)
{
    const int idx = blockIdx.x * 256 + threadIdx.x;      // 0..32767
    const int buf = idx >> 14;
    const int rem = idx & 16383;
    const int r4 = rem & 3;
    const int r = (r4 < 2) ? r4 : 400 + r4;
    const int plane = rem >> 2;
    (buf ? Tb : Ta)[(size_t)plane * RP + r] = make_uint4(0u, 0u, 0u, 0u);
}

// ---------------------------------------------------------------------------
// Pack conv weights w[o][i][k] f32 -> granules gi = t*1536 + ih*768 + k*256 + o,
// elems e: w[o][t*16+ih*8+e][k]. 24576 granules.
// ---------------------------------------------------------------------------
__global__ __launch_bounds__(256) void prep_w_pack_k(
    const float* __restrict__ w, uint4* __restrict__ dst)
{
    const int gi = blockIdx.x * 256 + threadIdx.x;
    if (gi >= 24576) return;
    const int t = gi / 1536;
    const int rem = gi - t * 1536;
    const int ih = rem / 768;
    const int rem2 = rem - ih * 768;
    const int k = rem2 >> 8, o = rem2 & 255;
    const int ibase = t * 16 + ih * 8;
    float v[8];
#pragma unroll
    for (int e = 0; e < 8; ++e) v[e] = w[(size_t)(o * CC + ibase + e) * 3 + k];
    uint4 p;
    p.x = pk2(v[0], v[1]); p.y = pk2(v[2], v[3]);
    p.z = pk2(v[4], v[5]); p.w = pk2(v[6], v[7]);
    dst[gi] = p;
}

// Pack Wl[k][n] f32 -> gi = t*512 + bh*256 + n, elems e: Wl[t*16+bh*8+e][n].
__global__ __launch_bounds__(256) void prep_wl_pack_k(
    const float* __restrict__ wl, uint4* __restrict__ dst)
{
    const int gi = blockIdx.x * 256 + threadIdx.x;       // < 32768
    const int t = gi >> 9;
    const int rem = gi & 511;
    const int bh = rem >> 8, n = rem & 255;
    const int kbase = t * 16 + bh * 8;
    float v[8];
#pragma unroll
    for (int e = 0; e < 8; ++e) v[e] = wl[(size_t)(kbase + e) * CC + n];
    uint4 p;
    p.x = pk2(v[0], v[1]); p.y = pk2(v[2], v[3]);
    p.z = pk2(v[4], v[5]); p.w = pk2(v[6], v[7]);
    dst[gi] = p;
}

// ---------------------------------------------------------------------------
// GEMM: emb[m][:] @ Wl + bl -> packed f16 activations. M=51200 K=1024 N=256.
// mfma 32x32x16 f16, tile 128m x 256n, K-step 16, double-buffered.
// B staged via global_load_lds (8 chunks); A reg-staged (f32->f16 convert).
// ---------------------------------------------------------------------------
__global__ __launch_bounds__(256, 2) void gemm_mfma_k(
    const float* __restrict__ A, const uint4* __restrict__ BP,
    const float* __restrict__ bias, u16* __restrict__ out)
{
    __shared__ uint4 As[2][2][128];
    __shared__ uint4 Bs[2][2][256];
    const int tid = threadIdx.x;
    const int lane = tid & 63, wid = tid >> 6;
    const int wl = wid >> 1, wo = wid & 1;
    const int ln = lane & 31, lp = lane >> 5;
    const int m0 = blockIdx.x * 128;

    const int ar = tid >> 1, ah = tid & 1;

    f32x16 acc[2][4];
#pragma unroll
    for (int i = 0; i < 2; ++i)
#pragma unroll
        for (int j = 0; j < 4; ++j) acc[i][j] = (f32x16)(0.f);

    float av[8];

    auto stageB = [&](int t, int buf) {
        const uint4* src = BP + t * 512;
        uint4* dst = &Bs[buf][0][0];
#pragma unroll
        for (int q = 0; q < 2; ++q) {
            const int c = wid * 2 + q;
            gld16(src + c * 64 + lane, dst + c * 64);
        }
    };
    auto loadA = [&](int i0) {
        const float* asrc = A + (size_t)(m0 + ar) * DD + i0 + ah * 8;
        *reinterpret_cast<float4*>(&av[0]) = *reinterpret_cast<const float4*>(asrc);
        *reinterpret_cast<float4*>(&av[4]) = *reinterpret_cast<const float4*>(asrc + 4);
    };
    auto writeA = [&](int buf) {
        uint4 p;
        p.x = pk2(av[0], av[1]); p.y = pk2(av[2], av[3]);
        p.z = pk2(av[4], av[5]); p.w = pk2(av[6], av[7]);
        As[buf][ah][ar] = p;
    };

    stageB(0, 0);
    loadA(0);
    writeA(0);
    __syncthreads();

    for (int t = 0; t < 64; ++t) {
        const int buf = t & 1;
        if (t < 63) {
            stageB(t + 1, buf ^ 1);
            loadA((t + 1) * 16);
        }
        f16x8 af0 = *reinterpret_cast<const f16x8*>(&As[buf][lp][wl * 64 + ln]);
        f16x8 af1 = *reinterpret_cast<const f16x8*>(&As[buf][lp][wl * 64 + 32 + ln]);
#pragma unroll
        for (int fo = 0; fo < 4; ++fo) {
            f16x8 bf = *reinterpret_cast<const f16x8*>(&Bs[buf][lp][wo * 128 + fo * 32 + ln]);
            acc[0][fo] = __builtin_amdgcn_mfma_f32_32x32x16_f16(af0, bf, acc[0][fo], 0, 0, 0);
            acc[1][fo] = __builtin_amdgcn_mfma_f32_32x32x16_f16(af1, bf, acc[1][fo], 0, 0, 0);
        }
        if (t < 63) writeA(buf ^ 1);
        __syncthreads();
    }

#pragma unroll
    for (int fl = 0; fl < 2; ++fl) {
        const int mbase = m0 + wl * 64 + fl * 32;
#pragma unroll
        for (int fo = 0; fo < 4; ++fo) {
            const int n = wo * 128 + fo * 32 + ln;
            const float bv = bias[n];
            const int nc = n >> 4, nh = (n >> 3) & 1, ne = n & 7;
#pragma unroll
            for (int r = 0; r < 16; ++r) {
                const int mrow = mbase + (r & 3) + 8 * (r >> 2) + 4 * lp;
                const int b = mrow / LL;
                const int l = mrow - b * LL;
                const size_t gr = ((size_t)(b * 16 + nc) * 2 + nh) * RP + l + 2;
                out[gr * 8 + ne] = f2h(acc[fl][fo][r] + bv);
            }
        }
    }
}

// ---------------------------------------------------------------------------
// Conv1d k=3 dil DIL as 3 shifted GEMMs, mfma 32x32x16 f16, packed act layout.
// Tile 128 l x 256 o; 16 K-steps of 16 i; double-buffered; ALL staging via
// global_load_lds: 29 chunks/step (5 X incl. junk tail + 24 W), round-robin
// over 4 waves. OOB rows handled by clamping to the zero pad row (r=403).
// ---------------------------------------------------------------------------
template<int DIL, bool RELU, bool F32OUT>
__global__ __launch_bounds__(256, 2) void conv_mfma_k(
    const uint4* __restrict__ X4, const uint4* __restrict__ W4,
    const float* __restrict__ bias, void* __restrict__ Yv)
{
    __shared__ uint4 XS[2][2][160];   // [buf][ih][row], rows 0..131 real, 132..159 junk
    __shared__ uint4 WS[2][2][768];   // [buf][ih][k*256+o]
    const int tid = threadIdx.x;
    const int lane = tid & 63, wid = tid >> 6;
    const int wl = wid >> 1, wo = wid & 1;
    const int ln = lane & 31, lp = lane >> 5;
    const int b = blockIdx.y, l0 = blockIdx.x * 128;

    f32x16 acc[2][4];
#pragma unroll
    for (int i = 0; i < 2; ++i)
#pragma unroll
        for (int j = 0; j < 4; ++j) acc[i][j] = (f32x16)(0.f);

    auto stage = [&](int t, int buf) {
        uint4* xdst = &XS[buf][0][0];            // 320 granules
        uint4* wdst = &WS[buf][0][0];            // 1536 granules
        const uint4* wsrc = W4 + t * 1536;
        const size_t xplane = ((size_t)(b * 16 + t)) * 2;
        for (int c = wid; c < 29; c += 4) {
            if (c < 5) {
                const int gidx = c * 64 + lane;
                const int ih = (gidx >= 160) ? 1 : 0;
                const int row = gidx - 160 * ih;
                const int r = min(l0 + row, 403);
                gld16(X4 + (xplane + ih) * RP + r, xdst + c * 64);
            } else {
                const int gidx = (c - 5) * 64 + lane;
                gld16(wsrc + gidx, wdst + (c - 5) * 64);
            }
        }
    };

    stage(0, 0);
    __syncthreads();

    for (int t = 0; t < 16; ++t) {
        const int buf = t & 1;
        if (t < 15) stage(t + 1, buf ^ 1);
#pragma unroll
        for (int s = 0; s < 3; ++s) {
            const int sh = 2 + (s - 1) * DIL;
            f16x8 a0 = *reinterpret_cast<const f16x8*>(&XS[buf][lp][wl * 64 + ln + sh]);
            f16x8 a1 = *reinterpret_cast<const f16x8*>(&XS[buf][lp][wl * 64 + 32 + ln + sh]);
#pragma unroll
            for (int fo = 0; fo < 4; ++fo) {
                f16x8 bf = *reinterpret_cast<const f16x8*>(&WS[buf][lp][s * 256 + wo * 128 + fo * 32 + ln]);
                acc[0][fo] = __builtin_amdgcn_mfma_f32_32x32x16_f16(a0, bf, acc[0][fo], 0, 0, 0);
                acc[1][fo] = __builtin_amdgcn_mfma_f32_32x32x16_f16(a1, bf, acc[1][fo], 0, 0, 0);
            }
        }
        __syncthreads();
    }

#pragma unroll
    for (int fl = 0; fl < 2; ++fl) {
        const int lbase = l0 + wl * 64 + fl * 32;
#pragma unroll
        for (int fo = 0; fo < 4; ++fo) {
            const int o = wo * 128 + fo * 32 + ln;
            const float bv = bias[o];
            const int oc = o >> 4, oh = (o >> 3) & 1, oe = o & 7;
#pragma unroll
            for (int r = 0; r < 16; ++r) {
                const int l = lbase + (r & 3) + 8 * (r >> 2) + 4 * lp;
                if (l < LL) {
                    float v = acc[fl][fo][r] + bv;
                    if (RELU) v = fmaxf(v, 0.f);
                    if (F32OUT) {
                        ((float*)Yv)[((size_t)b * LL + l) * CC + o] = v;
                    } else {
                        const size_t gr = ((size_t)(b * 16 + oc) * 2 + oh) * RP + l + 2;
                        ((u16*)Yv)[gr * 8 + oe] = f2h(v);
                    }
                }
            }
        }
    }
}

// ---------------------------------------------------------------------------
// LayerNorm over l (torch ddof=1, /(std+eps)) on packed layout, in place.
// One wave per (b, ic); two-pass from registers; stats via shfl_xor.
// ---------------------------------------------------------------------------
__global__ __launch_bounds__(64) void ln_k(
    uint4* __restrict__ A4, const float* __restrict__ g, const float* __restrict__ be)
{
    const int bx = blockIdx.x;                 // b*16 + ic
    const int ln = threadIdx.x;
    const int ih = ln & 1, half = ln >> 1;
    uint4* base = A4 + ((size_t)bx * 2 + ih) * RP;

    float s[8], q[8];
#pragma unroll
    for (int e = 0; e < 8; ++e) { s[e] = 0.f; q[e] = 0.f; }
    uint4 xg[13];
    float gv[13], bv[13];

#pragma unroll
    for (int it = 0; it < 13; ++it) {
        const int r = 2 + it * 32 + half;
        const bool act = (r < 402);
        uint4 v = act ? base[r] : make_uint4(0u, 0u, 0u, 0u);
        gv[it] = act ? g[r - 2] : 0.f;
        bv[it] = act ? be[r - 2] : 0.f;
        xg[it] = v;
        const u32 w[4] = {v.x, v.y, v.z, v.w};
#pragma unroll
        for (int p = 0; p < 4; ++p) {
            const float f0 = h2f((u16)(w[p] & 0xffff));
            const float f1 = h2f((u16)(w[p] >> 16));
            s[2 * p] += f0;     q[2 * p] = fmaf(f0, f0, q[2 * p]);
            s[2 * p + 1] += f1; q[2 * p + 1] = fmaf(f1, f1, q[2 * p + 1]);
        }
    }
#pragma unroll
    for (int off = 2; off < 64; off <<= 1) {
#pragma unroll
        for (int e = 0; e < 8; ++e) {
            s[e] += __shfl_xor(s[e], off);
            q[e] += __shfl_xor(q[e], off);
        }
    }
    float mean[8], inv[8];
#pragma unroll
    for (int e = 0; e < 8; ++e) {
        mean[e] = s[e] * (1.f / LL);
        const float var = (q[e] - s[e] * mean[e]) * (1.f / (LL - 1));
        inv[e] = 1.f / (sqrtf(fmaxf(var, 0.f)) + 1e-6f);
    }
#pragma unroll
    for (int it = 0; it < 13; ++it) {
        const int r = 2 + it * 32 + half;
        if (r < 402) {
            const uint4 v = xg[it];
            const u32 w[4] = {v.x, v.y, v.z, v.w};
            const float gl = gv[it], bl = bv[it];
            uint4 o;
            u32 ow[4];
#pragma unroll
            for (int p = 0; p < 4; ++p) {
                const float f0 = h2f((u16)(w[p] & 0xffff));
                const float f1 = h2f((u16)(w[p] >> 16));
                const float y0 = fmaf(gl, (f0 - mean[2 * p]) * inv[2 * p], bl);
                const float y1 = fmaf(gl, (f1 - mean[2 * p + 1]) * inv[2 * p + 1], bl);
                ow[p] = pk2(y0, y1);
            }
            o.x = ow[0]; o.y = ow[1]; o.z = ow[2]; o.w = ow[3];
            base[r] = o;
        }
    }
}

// ---------------------------------------------------------------------------
extern "C" void kernel_launch(void* const* d_in, const int* in_sizes, int n_in,
                              void* d_out, int out_size, void* d_ws, size_t ws_size,
                              hipStream_t stream)
{
    (void)in_sizes; (void)n_in; (void)out_size; (void)ws_size;

    const float* emb = (const float*)d_in[0];
    const float* Wl  = (const float*)d_in[2];
    const float* bl  = (const float*)d_in[3];
    const float* w0  = (const float*)d_in[4];
    const float* b0  = (const float*)d_in[5];
    const float* w1  = (const float*)d_in[6];
    const float* b1  = (const float*)d_in[7];
    const float* w2  = (const float*)d_in[8];
    const float* b2  = (const float*)d_in[9];
    const float* g1  = (const float*)d_in[10];
    const float* be1 = (const float*)d_in[11];
    const float* g2  = (const float*)d_in[12];
    const float* be2 = (const float*)d_in[13];

    uint4* Ta = (uint4*)d_out;                  // packed f16 act ping
    uint4* Tb = (uint4*)d_ws;                   // packed f16 act pong
    uint4* WB0 = Tb + ACT_GRANULES;
    uint4* WB1 = WB0 + 24576;
    uint4* WB2 = WB1 + 24576;
    uint4* WlP = WB2 + 24576;

    pad_zero_k<<<128, 256, 0, stream>>>(Ta, Tb);
    prep_w_pack_k<<<96, 256, 0, stream>>>(w0, WB0);
    prep_w_pack_k<<<96, 256, 0, stream>>>(w1, WB1);
    prep_w_pack_k<<<96, 256, 0, stream>>>(w2, WB2);
    prep_wl_pack_k<<<128, 256, 0, stream>>>(Wl, WlP);

    gemm_mfma_k<<<(BN * LL) / 128, 256, 0, stream>>>(emb, WlP, bl, (u16*)Ta);

    const dim3 cg(4, BN);
    auto ln = [&](uint4* buf, const float* g, const float* be) {
        ln_k<<<16 * BN, 64, 0, stream>>>(buf, g, be);
    };

    // net1 (+outer relu fused into c3) + LN(g2)
    conv_mfma_k<1, true,  false><<<cg, 256, 0, stream>>>(Ta, WB0, b0, Tb);
    ln(Tb, g1, be1);
    conv_mfma_k<1, false, false><<<cg, 256, 0, stream>>>(Tb, WB1, b1, Ta);
    conv_mfma_k<2, true,  false><<<cg, 256, 0, stream>>>(Ta, WB2, b2, Tb);
    ln(Tb, g2, be2);
    // net2
    conv_mfma_k<1, true,  false><<<cg, 256, 0, stream>>>(Tb, WB0, b0, Ta);
    ln(Ta, g1, be1);
    conv_mfma_k<1, false, false><<<cg, 256, 0, stream>>>(Ta, WB1, b1, Tb);
    conv_mfma_k<2, false, false><<<cg, 256, 0, stream>>>(Tb, WB2, b2, Ta);
    // net3
    conv_mfma_k<1, true,  false><<<cg, 256, 0, stream>>>(Ta, WB0, b0, Tb);
    ln(Tb, g1, be1);
    conv_mfma_k<1, false, false><<<cg, 256, 0, stream>>>(Tb, WB1, b1, Ta);
    conv_mfma_k<2, false, false><<<cg, 256, 0, stream>>>(Ta, WB2, b2, Tb);
    // net4 -> final conv reads Tb(=d_ws), writes f32 [B][L][C] to d_out
    conv_mfma_k<1, true,  false><<<cg, 256, 0, stream>>>(Tb, WB0, b0, Ta);
    ln(Ta, g1, be1);
    conv_mfma_k<1, false, false><<<cg, 256, 0, stream>>>(Ta, WB1, b1, Tb);
    conv_mfma_k<2, false, true ><<<cg, 256, 0, stream>>>(Tb, WB2, b2, (float*)d_out);
}